// Round 9
// baseline (105.022 us; speedup 1.0000x reference)
//
#include <hip/hip_runtime.h>
#include <hip/hip_bf16.h>
#include <math.h>

// Problem constants
#define BB 32
#define SS 16384
#define MM 64
#define HID 512
#define EPSV 1e-8f

// ws layout (in floats)
#define OFF_H    0                 // 32*512 h vectors
#define OFF_P    16384             // 32*512 per-batch params (sparse, see below)
#define OFF_SGRP 32768             // 32*128 per-chunk wgam_r partial sums
#define OFF_SGWP (OFF_SGRP + BB*128)
#define OFF_RP   (OFF_SGWP + BB*128)      // 32*64*64 per-chunk r partials (update grid)
#define OFF_WGR  (OFF_RP + BB*64*64)      // 32*16384
#define OFF_WGW  (OFF_WGR + BB*SS)        // 32*16384; total ~4.9 MB
//
// P-region per-batch layout (512 floats):
//  [0..63]   k_r            [64] beta_r  [69] gamma_r   [96..98] raw shift_r
//  [128..191] k_w           [192] beta_w [197] gamma_w  [224..226] raw shift_w
//  [256..319] erase         [320..383] add

__device__ __forceinline__ float sigmoidf_(float x) { return 1.f / (1.f + expf(-x)); }
__device__ __forceinline__ float softplusf_(float x) {
    return (x > 0.f) ? x + log1pf(expf(-x)) : log1pf(expf(x));
}

// One wave per (b,t): h[b][t].
__global__ void k_lstm(const float* __restrict__ x, const float* __restrict__ pdo,
                       const float* __restrict__ prv,
                       const float* __restrict__ W_ih, const float* __restrict__ b_ih,
                       const float* __restrict__ b_hh, float* __restrict__ ws) {
    int wid = blockIdx.x * 4 + (threadIdx.x >> 6);   // 0 .. 32*512-1
    int lane = threadIdx.x & 63;
    int b = wid >> 9, t = wid & 511;
    float x0 = x[b * 64 + lane];
    float x1 = pdo[b * 64 + lane];
    float x2 = prv[b * 64 + lane];
    const float* wi = W_ih + (size_t)t * 192;
    const float* wg = W_ih + (size_t)(1024 + t) * 192;
    const float* wo = W_ih + (size_t)(1536 + t) * 192;
    float zi = x0 * wi[lane] + x1 * wi[64 + lane] + x2 * wi[128 + lane];
    float zg = x0 * wg[lane] + x1 * wg[64 + lane] + x2 * wg[128 + lane];
    float zo = x0 * wo[lane] + x1 * wo[64 + lane] + x2 * wo[128 + lane];
    #pragma unroll
    for (int off = 32; off >= 1; off >>= 1) {
        zi += __shfl_xor(zi, off);
        zg += __shfl_xor(zg, off);
        zo += __shfl_xor(zo, off);
    }
    if (lane == 0) {
        zi += b_ih[t] + b_hh[t];
        zg += b_ih[1024 + t] + b_hh[1024 + t];
        zo += b_ih[1536 + t] + b_hh[1536 + t];
        float c = sigmoidf_(zi) * tanhf(zg);
        ws[OFF_H + (size_t)b * 512 + t] = sigmoidf_(zo) * tanhf(c);
    }
}

// One wave per (b, head-row j): j<70 read head, else write head row j-70.
__global__ void k_heads(const float* __restrict__ W_r, const float* __restrict__ b_r,
                        const float* __restrict__ W_w, const float* __restrict__ b_w,
                        float* __restrict__ ws) {
    int wid = blockIdx.x * 4 + (threadIdx.x >> 6);   // 0 .. 32*268-1
    int lane = threadIdx.x & 63;
    int b = wid / 268, j = wid % 268;
    const float* h = ws + OFF_H + (size_t)b * 512;
    const float* wrow;
    float bias;
    if (j < 70) { wrow = W_r + (size_t)j * 512; bias = b_r[j]; }
    else        { wrow = W_w + (size_t)(j - 70) * 512; bias = b_w[j - 70]; }
    float acc = 0.f;
    #pragma unroll
    for (int c = 0; c < 8; c++) acc = fmaf(h[c * 64 + lane], wrow[c * 64 + lane], acc);
    #pragma unroll
    for (int off = 32; off >= 1; off >>= 1) acc += __shfl_xor(acc, off);
    if (lane != 0) return;
    acc += bias;
    float* P = ws + OFF_P + (size_t)b * 512;
    if (j < 70) {
        if (j < 64)       P[j] = acc;                       // k_r
        else if (j == 64) P[64] = softplusf_(acc);          // beta_r
        else if (j == 65) P[65] = sigmoidf_(acc);           // g_r (cancels; unused)
        else if (j <= 68) P[96 + (j - 66)] = acc;           // raw shift_r
        else              P[69] = 1.f + softplusf_(acc);    // gamma_r
    } else {
        int jj = j - 70;
        if (jj < 64)       P[128 + jj] = acc;               // k_w
        else if (jj == 64) P[192] = softplusf_(acc);        // beta_w
        else if (jj == 65) P[193] = sigmoidf_(acc);         // g_w (cancels; unused)
        else if (jj <= 68) P[224 + (jj - 66)] = acc;        // raw shift_w
        else if (jj == 69) P[197] = 1.f + softplusf_(acc);  // gamma_w
        else if (jj < 134) P[256 + (jj - 70)] = acc;        // erase
        else               P[320 + (jj - 134)] = acc;       // add
    }
}

// Fused scores+conv+sharpen. Coalesced global loads (16-deep MLP) -> XOR-
// swizzled LDS tile -> one ROW PER THREAD from LDS (zero shuffles, all lanes
// do productive exp). Keys read wave-uniform (scalar cache). Per-chunk sums.
// E = exp(beta*(cos-1)); wgam = (conv(s,E))^gamma; softmax denom & g cancel.
__global__ void __launch_bounds__(128, 2)
k_scorewgam(const float* __restrict__ mem, float* __restrict__ ws) {
    int b = blockIdx.x >> 7;          // 128 chunks of 128 rows per batch
    int chunk = blockIdx.x & 127;
    int tid = threadIdx.x;            // 0..127
    const float* P = ws + OFF_P + (size_t)b * 512;
    int row0 = chunk * 128;

    __shared__ float4 tile[128 * 16];   // 32 KB, XOR-swizzled rows
    __shared__ float sh_er[130], sh_ew[130];
    __shared__ float par[8];   // ikr, ikw, sr0..2, sw0..2
    __shared__ float lr[2], lw[2];

    // 1. issue the block's 32 KB of coalesced loads FIRST (16-deep pipeline)
    const float4* src = (const float4*)(mem + ((size_t)b * SS + row0) * 64);
    float4 st[16];
    #pragma unroll
    for (int j = 0; j < 16; ++j) st[j] = src[tid + j * 128];

    // 2. prologue on wave 0: key norms + shift softmaxes
    if (tid < 64) {
        float kr = P[tid], kw = P[128 + tid];
        float nr = kr * kr, nw = kw * kw;
        #pragma unroll
        for (int off = 32; off >= 1; off >>= 1) {
            nr += __shfl_xor(nr, off);
            nw += __shfl_xor(nw, off);
        }
        if (tid == 0) {
            par[0] = 1.f / fmaxf(sqrtf(nr), EPSV);
            par[1] = 1.f / fmaxf(sqrtf(nw), EPSV);
            float s0 = softplusf_(P[96]), s1 = softplusf_(P[97]), s2 = softplusf_(P[98]);
            float mx = fmaxf(s0, fmaxf(s1, s2));
            float e0 = expf(s0 - mx), e1 = expf(s1 - mx), e2 = expf(s2 - mx);
            float si = 1.f / (e0 + e1 + e2);
            par[2] = e0 * si; par[3] = e1 * si; par[4] = e2 * si;
            s0 = softplusf_(P[224]); s1 = softplusf_(P[225]); s2 = softplusf_(P[226]);
            mx = fmaxf(s0, fmaxf(s1, s2));
            e0 = expf(s0 - mx); e1 = expf(s1 - mx); e2 = expf(s2 - mx);
            si = 1.f / (e0 + e1 + e2);
            par[5] = e0 * si; par[6] = e1 * si; par[7] = e2 * si;
        }
    }
    float beta_r = P[64], beta_w = P[192];
    float gamma_r = P[69], gamma_w = P[197];

    // 3. halo rows row0-1 and row0+128 (lanes 0..31 of wave 0; par[] is
    //    wave-coherent here: written by lane 0 of this same wave above)
    if (tid < 32) {
        int grp = tid >> 4, c = tid & 15;
        int hrow = grp ? ((row0 + 128) & (SS - 1)) : ((row0 - 1) & (SS - 1));
        float4 m4 = *(const float4*)(mem + ((size_t)b * SS + hrow) * 64 + c * 4);
        float4 kr4 = *(const float4*)(P + c * 4);
        float4 kw4 = *(const float4*)(P + 128 + c * 4);
        float dr = m4.x * kr4.x + m4.y * kr4.y + m4.z * kr4.z + m4.w * kr4.w;
        float dw = m4.x * kw4.x + m4.y * kw4.y + m4.z * kw4.z + m4.w * kw4.w;
        float n2 = m4.x * m4.x + m4.y * m4.y + m4.z * m4.z + m4.w * m4.w;
        #pragma unroll
        for (int off = 8; off >= 1; off >>= 1) {
            dr += __shfl_xor(dr, off);
            dw += __shfl_xor(dw, off);
            n2 += __shfl_xor(n2, off);
        }
        if (c == 0) {
            float imn = 1.f / fmaxf(sqrtf(n2), EPSV);
            int slot = grp ? 129 : 0;
            sh_er[slot] = exp2f(1.44269504f * beta_r * (dr * par[0] * imn - 1.f));
            sh_ew[slot] = exp2f(1.44269504f * beta_w * (dw * par[1] * imn - 1.f));
        }
    }

    // 4. store staged data to LDS, XOR-swizzled within each row
    #pragma unroll
    for (int j = 0; j < 16; ++j) {
        int idx = tid + j * 128;
        int r = idx >> 4, c4 = idx & 15;
        tile[r * 16 + (c4 ^ (r & 15))] = st[j];
    }
    __syncthreads();
    float ikr = par[0], ikw = par[1];

    // 5. compute: thread owns row tid; swizzled reads spread banks; keys are
    //    wave-uniform loads from P (scalar-cached)
    {
        int r = tid, rx = tid & 15;
        const float4* Pk = (const float4*)P;          // k_r as 16 float4
        const float4* Pw = (const float4*)(P + 128);  // k_w as 16 float4
        float dr = 0.f, dw = 0.f, n2 = 0.f;
        #pragma unroll
        for (int k = 0; k < 16; ++k) {
            float4 m4 = tile[r * 16 + (k ^ rx)];
            float4 kr4 = Pk[k];
            float4 kw4 = Pw[k];
            dr = fmaf(m4.x, kr4.x, fmaf(m4.y, kr4.y, fmaf(m4.z, kr4.z, fmaf(m4.w, kr4.w, dr))));
            dw = fmaf(m4.x, kw4.x, fmaf(m4.y, kw4.y, fmaf(m4.z, kw4.z, fmaf(m4.w, kw4.w, dw))));
            n2 = fmaf(m4.x, m4.x, fmaf(m4.y, m4.y, fmaf(m4.z, m4.z, fmaf(m4.w, m4.w, n2))));
        }
        float imn = 1.f / fmaxf(sqrtf(n2), EPSV);
        sh_er[1 + r] = exp2f(1.44269504f * beta_r * (dr * ikr * imn - 1.f));
        sh_ew[1 + r] = exp2f(1.44269504f * beta_w * (dw * ikw * imn - 1.f));
    }
    __syncthreads();

    // 6. conv + sharpen for row s = row0 + tid (fast pow: base > 0)
    float cvr = par[2] * sh_er[tid] + par[3] * sh_er[tid + 1] + par[4] * sh_er[tid + 2];
    float cvw = par[5] * sh_ew[tid] + par[6] * sh_ew[tid + 1] + par[7] * sh_ew[tid + 2];
    float wgr = exp2f(gamma_r * log2f(cvr));
    float wgw = exp2f(gamma_w * log2f(cvw));
    ws[OFF_WGR + (size_t)b * SS + row0 + tid] = wgr;
    ws[OFF_WGW + (size_t)b * SS + row0 + tid] = wgw;

    int w = tid >> 6, lane = tid & 63;
    float rr = wgr, rw2 = wgw;
    #pragma unroll
    for (int off = 32; off >= 1; off >>= 1) {
        rr += __shfl_xor(rr, off);
        rw2 += __shfl_xor(rw2, off);
    }
    if (lane == 0) { lr[w] = rr; lw[w] = rw2; }
    __syncthreads();
    if (tid == 0) {
        ws[OFF_SGRP + b * 128 + chunk] = lr[0] + lr[1];
        ws[OFF_SGWP + b * 128 + chunk] = lw[0] + lw[1];
    }
}

// Final weights; r partials; new_mem = mem*(1-w_w*e)+w_w*a.
__global__ void k_update(const float* __restrict__ mem, float* __restrict__ ws,
                         float* __restrict__ out) {
    int b = blockIdx.x >> 6, chunk = blockIdx.x & 63, tid = threadIdx.x;
    int rowslot = tid >> 4, col = tid & 15;
    const float* P = ws + OFF_P + (size_t)b * 512;
    float4 er4 = *(const float4*)(P + 256 + col * 4);
    float4 ad4 = *(const float4*)(P + 320 + col * 4);

    // reduce 128 per-chunk wgam sums -> 1/sum
    __shared__ float sinv[2];
    if (tid < 64) {
        float v = ws[OFF_SGRP + b * 128 + tid] + ws[OFF_SGRP + b * 128 + 64 + tid];
        #pragma unroll
        for (int off = 32; off >= 1; off >>= 1) v += __shfl_xor(v, off);
        if (tid == 0) sinv[0] = 1.f / v;
    } else if (tid < 128) {
        int t2 = tid - 64;
        float v = ws[OFF_SGWP + b * 128 + t2] + ws[OFF_SGWP + b * 128 + 64 + t2];
        #pragma unroll
        for (int off = 32; off >= 1; off >>= 1) v += __shfl_xor(v, off);
        if (tid == 64) sinv[1] = 1.f / v;
    }
    __syncthreads();
    float isr = sinv[0], isw = sinv[1];

    const float* wgr = ws + OFF_WGR + (size_t)b * SS;
    const float* wgw = ws + OFF_WGW + (size_t)b * SS;
    float* nm = out + 2048 + (size_t)b * SS * 64;
    float4 racc = {0.f, 0.f, 0.f, 0.f};
    int row0 = chunk * 256;
    for (int it = 0; it < 16; ++it) {
        int row = row0 + it * 16 + rowslot;
        float wr = wgr[row] * isr;
        float ww = wgw[row] * isw;
        float4 v = *(const float4*)(mem + ((size_t)b * SS + row) * 64 + col * 4);
        racc.x = fmaf(wr, v.x, racc.x);
        racc.y = fmaf(wr, v.y, racc.y);
        racc.z = fmaf(wr, v.z, racc.z);
        racc.w = fmaf(wr, v.w, racc.w);
        float4 o4;
        o4.x = v.x * (1.f - ww * er4.x) + ww * ad4.x;
        o4.y = v.y * (1.f - ww * er4.y) + ww * ad4.y;
        o4.z = v.z * (1.f - ww * er4.z) + ww * ad4.z;
        o4.w = v.w * (1.f - ww * er4.w) + ww * ad4.w;
        *(float4*)(nm + (size_t)row * 64 + col * 4) = o4;
    }
    __shared__ float4 red[256];
    red[tid] = racc;
    __syncthreads();
    if (tid < 16) {
        float4 a = red[tid];
        for (int rs = 1; rs < 16; ++rs) {
            float4 t2 = red[rs * 16 + tid];
            a.x += t2.x; a.y += t2.y; a.z += t2.z; a.w += t2.w;
        }
        float* rp = ws + OFF_RP + ((size_t)b * 64 + chunk) * 64;
        rp[tid * 4 + 0] = a.x;
        rp[tid * 4 + 1] = a.y;
        rp[tid * 4 + 2] = a.z;
        rp[tid * 4 + 3] = a.w;
    }
}

// output = softmax(concat(h, r) @ W_o.T + b_o); one wave per batch.
__global__ void k_out(const float* __restrict__ ws, const float* __restrict__ W_o,
                      const float* __restrict__ b_o, float* __restrict__ out) {
    int b = blockIdx.x, o = threadIdx.x;  // 64 threads
    __shared__ float sh_r[64];
    float accr = 0.f;
    for (int c = 0; c < 64; ++c) accr += ws[OFF_RP + ((size_t)b * 64 + c) * 64 + o];
    sh_r[o] = accr;
    __syncthreads();
    const float* h = ws + OFF_H + (size_t)b * 512;
    const float* w = W_o + (size_t)o * 576;
    float acc = b_o[o];
    for (int t = 0; t < 512; t++) acc = fmaf(h[t], w[t], acc);
    for (int m = 0; m < 64; m++) acc = fmaf(sh_r[m], w[512 + m], acc);
    float mx = acc;
    #pragma unroll
    for (int off = 32; off >= 1; off >>= 1) mx = fmaxf(mx, __shfl_xor(mx, off));
    float e = expf(acc - mx);
    float sm = e;
    #pragma unroll
    for (int off = 32; off >= 1; off >>= 1) sm += __shfl_xor(sm, off);
    out[b * 64 + o] = e / sm;
}

extern "C" void kernel_launch(void* const* d_in, const int* in_sizes, int n_in,
                              void* d_out, int out_size, void* d_ws, size_t ws_size,
                              hipStream_t stream) {
    const float* x    = (const float*)d_in[0];
    const float* pdo  = (const float*)d_in[1];
    const float* prv  = (const float*)d_in[2];
    const float* mem  = (const float*)d_in[3];
    const float* W_ih = (const float*)d_in[4];
    // d_in[5] = W_hh (unused by reference math)
    const float* b_ih = (const float*)d_in[6];
    const float* b_hh = (const float*)d_in[7];
    const float* W_r  = (const float*)d_in[8];
    const float* b_r  = (const float*)d_in[9];
    const float* W_w  = (const float*)d_in[10];
    const float* b_w  = (const float*)d_in[11];
    const float* W_o  = (const float*)d_in[12];
    const float* b_o  = (const float*)d_in[13];
    float* out = (float*)d_out;
    float* ws  = (float*)d_ws;

    k_lstm<<<BB * 512 / 4, 256, 0, stream>>>(x, pdo, prv, W_ih, b_ih, b_hh, ws);
    k_heads<<<(BB * 268) / 4, 256, 0, stream>>>(W_r, b_r, W_w, b_w, ws);
    k_scorewgam<<<BB * 128, 128, 0, stream>>>(mem, ws);
    k_update<<<BB * 64, 256, 0, stream>>>(mem, ws, out);
    k_out<<<BB, 64, 0, stream>>>(ws, W_o, b_o, out);
}

// Round 10
// 99.501 us; speedup vs baseline: 1.0555x; 1.0555x over previous
//
#include <hip/hip_runtime.h>
#include <hip/hip_bf16.h>
#include <math.h>

// Problem constants
#define BB 32
#define SS 16384
#define MM 64
#define HID 512
#define EPSV 1e-8f

// ws layout (in floats)
#define OFF_H    0                 // 32*512 h vectors
#define OFF_P    16384             // 32*512 per-batch params (sparse, see below)
#define OFF_SGRP 32768             // 32*64 per-chunk wgam_r partial sums
#define OFF_SGWP (OFF_SGRP + BB*64)
#define OFF_RP   (OFF_SGWP + BB*64)       // 32*64*64 per-chunk r partials
#define OFF_WGR  (OFF_RP + BB*64*64)      // 32*16384
#define OFF_WGW  (OFF_WGR + BB*SS)        // 32*16384; total ~4.9 MB
//
// P-region per-batch layout (512 floats):
//  [0..63]   k_r            [64] beta_r  [69] gamma_r   [96..98] raw shift_r
//  [128..191] k_w           [192] beta_w [197] gamma_w  [224..226] raw shift_w
//  [256..319] erase         [320..383] add

__device__ __forceinline__ float sigmoidf_(float x) { return 1.f / (1.f + expf(-x)); }
__device__ __forceinline__ float softplusf_(float x) {
    return (x > 0.f) ? x + log1pf(expf(-x)) : log1pf(expf(x));
}

// One wave per (b,t): h[b][t].
__global__ void k_lstm(const float* __restrict__ x, const float* __restrict__ pdo,
                       const float* __restrict__ prv,
                       const float* __restrict__ W_ih, const float* __restrict__ b_ih,
                       const float* __restrict__ b_hh, float* __restrict__ ws) {
    int wid = blockIdx.x * 4 + (threadIdx.x >> 6);   // 0 .. 32*512-1
    int lane = threadIdx.x & 63;
    int b = wid >> 9, t = wid & 511;
    float x0 = x[b * 64 + lane];
    float x1 = pdo[b * 64 + lane];
    float x2 = prv[b * 64 + lane];
    const float* wi = W_ih + (size_t)t * 192;
    const float* wg = W_ih + (size_t)(1024 + t) * 192;
    const float* wo = W_ih + (size_t)(1536 + t) * 192;
    float zi = x0 * wi[lane] + x1 * wi[64 + lane] + x2 * wi[128 + lane];
    float zg = x0 * wg[lane] + x1 * wg[64 + lane] + x2 * wg[128 + lane];
    float zo = x0 * wo[lane] + x1 * wo[64 + lane] + x2 * wo[128 + lane];
    #pragma unroll
    for (int off = 32; off >= 1; off >>= 1) {
        zi += __shfl_xor(zi, off);
        zg += __shfl_xor(zg, off);
        zo += __shfl_xor(zo, off);
    }
    if (lane == 0) {
        zi += b_ih[t] + b_hh[t];
        zg += b_ih[1024 + t] + b_hh[1024 + t];
        zo += b_ih[1536 + t] + b_hh[1536 + t];
        float c = sigmoidf_(zi) * tanhf(zg);
        ws[OFF_H + (size_t)b * 512 + t] = sigmoidf_(zo) * tanhf(c);
    }
}

// One wave per (b, head-row j): j<70 read head, else write head row j-70.
__global__ void k_heads(const float* __restrict__ W_r, const float* __restrict__ b_r,
                        const float* __restrict__ W_w, const float* __restrict__ b_w,
                        float* __restrict__ ws) {
    int wid = blockIdx.x * 4 + (threadIdx.x >> 6);   // 0 .. 32*268-1
    int lane = threadIdx.x & 63;
    int b = wid / 268, j = wid % 268;
    const float* h = ws + OFF_H + (size_t)b * 512;
    const float* wrow;
    float bias;
    if (j < 70) { wrow = W_r + (size_t)j * 512; bias = b_r[j]; }
    else        { wrow = W_w + (size_t)(j - 70) * 512; bias = b_w[j - 70]; }
    float acc = 0.f;
    #pragma unroll
    for (int c = 0; c < 8; c++) acc = fmaf(h[c * 64 + lane], wrow[c * 64 + lane], acc);
    #pragma unroll
    for (int off = 32; off >= 1; off >>= 1) acc += __shfl_xor(acc, off);
    if (lane != 0) return;
    acc += bias;
    float* P = ws + OFF_P + (size_t)b * 512;
    if (j < 70) {
        if (j < 64)       P[j] = acc;                       // k_r
        else if (j == 64) P[64] = softplusf_(acc);          // beta_r
        else if (j == 65) P[65] = sigmoidf_(acc);           // g_r (cancels; unused)
        else if (j <= 68) P[96 + (j - 66)] = acc;           // raw shift_r
        else              P[69] = 1.f + softplusf_(acc);    // gamma_r
    } else {
        int jj = j - 70;
        if (jj < 64)       P[128 + jj] = acc;               // k_w
        else if (jj == 64) P[192] = softplusf_(acc);        // beta_w
        else if (jj == 65) P[193] = sigmoidf_(acc);         // g_w (cancels; unused)
        else if (jj <= 68) P[224 + (jj - 66)] = acc;        // raw shift_w
        else if (jj == 69) P[197] = 1.f + softplusf_(acc);  // gamma_w
        else if (jj < 134) P[256 + (jj - 70)] = acc;        // erase
        else               P[320 + (jj - 134)] = acc;       // add
    }
}

// Fused scores+conv+sharpen. k_update-shaped main loop (coalesced tid*16B +
// it*4KB loads, zero cross-lane ops, independent iterations) with the row
// reduction done via transposed LDS partials (stride 260 -> 2-way banks, free).
// Phase B: thread == row, 48 independent ds_read_b32 + register tree sum.
// E = exp(beta*(cos-1)); wgam = (conv(s,E))^gamma; softmax denom & g cancel.
#define PST 260   // partial-array row stride (260 % 32 == 4 -> conflict-free)
__global__ void k_scorewgam(const float* __restrict__ mem, float* __restrict__ ws) {
    int b = blockIdx.x >> 6;
    int chunk = blockIdx.x & 63;
    int tid = threadIdx.x;            // 0..255
    const float* P = ws + OFF_P + (size_t)b * 512;
    int row0 = chunk * 256;

    __shared__ float pdr[16 * PST], pdw[16 * PST], pn2[16 * PST];  // 49.9 KB
    __shared__ float sh_er[258], sh_ew[258];
    __shared__ float par[8];   // ikr, ikw, sr0..2, sw0..2
    __shared__ float lr[4], lw[4];

    // prologue on wave 0: key norms + shift softmaxes
    if (tid < 64) {
        float kr = P[tid], kw = P[128 + tid];
        float nr = kr * kr, nw = kw * kw;
        #pragma unroll
        for (int off = 32; off >= 1; off >>= 1) {
            nr += __shfl_xor(nr, off);
            nw += __shfl_xor(nw, off);
        }
        if (tid == 0) {
            par[0] = 1.f / fmaxf(sqrtf(nr), EPSV);
            par[1] = 1.f / fmaxf(sqrtf(nw), EPSV);
            float s0 = softplusf_(P[96]), s1 = softplusf_(P[97]), s2 = softplusf_(P[98]);
            float mx = fmaxf(s0, fmaxf(s1, s2));
            float e0 = expf(s0 - mx), e1 = expf(s1 - mx), e2 = expf(s2 - mx);
            float si = 1.f / (e0 + e1 + e2);
            par[2] = e0 * si; par[3] = e1 * si; par[4] = e2 * si;
            s0 = softplusf_(P[224]); s1 = softplusf_(P[225]); s2 = softplusf_(P[226]);
            mx = fmaxf(s0, fmaxf(s1, s2));
            e0 = expf(s0 - mx); e1 = expf(s1 - mx); e2 = expf(s2 - mx);
            si = 1.f / (e0 + e1 + e2);
            par[5] = e0 * si; par[6] = e1 * si; par[7] = e2 * si;
        }
    }
    float beta_r = P[64], beta_w = P[192];
    float gamma_r = P[69], gamma_w = P[197];

    // halo rows row0-1 and row0+256 (wave 0; par[] is wave-coherent here)
    if (tid < 32) {
        int grp = tid >> 4, c = tid & 15;
        int hrow = grp ? ((row0 + 256) & (SS - 1)) : ((row0 - 1) & (SS - 1));
        float4 m4 = *(const float4*)(mem + ((size_t)b * SS + hrow) * 64 + c * 4);
        float4 kr4 = *(const float4*)(P + c * 4);
        float4 kw4 = *(const float4*)(P + 128 + c * 4);
        float dr = m4.x * kr4.x + m4.y * kr4.y + m4.z * kr4.z + m4.w * kr4.w;
        float dw = m4.x * kw4.x + m4.y * kw4.y + m4.z * kw4.z + m4.w * kw4.w;
        float n2 = m4.x * m4.x + m4.y * m4.y + m4.z * m4.z + m4.w * m4.w;
        #pragma unroll
        for (int off = 8; off >= 1; off >>= 1) {
            dr += __shfl_xor(dr, off);
            dw += __shfl_xor(dw, off);
            n2 += __shfl_xor(n2, off);
        }
        if (c == 0) {
            float imn = 1.f / fmaxf(sqrtf(n2), EPSV);
            int slot = grp ? 257 : 0;
            sh_er[slot] = exp2f(1.44269504f * beta_r * (dr * par[0] * imn - 1.f));
            sh_ew[slot] = exp2f(1.44269504f * beta_w * (dw * par[1] * imn - 1.f));
        }
    }

    // phase A: update-shaped loop; store per-(row,col) partials to LDS
    int rowslot = tid >> 4, col = tid & 15;
    float4 kr4 = *(const float4*)(P + col * 4);
    float4 kw4 = *(const float4*)(P + 128 + col * 4);
    const float4* base = (const float4*)(mem + ((size_t)b * SS + row0) * 64) + tid;
    #pragma unroll
    for (int it = 0; it < 16; ++it) {
        float4 v = base[it * 256];
        int row = it * 16 + rowslot;
        pdr[col * PST + row] = v.x * kr4.x + v.y * kr4.y + v.z * kr4.z + v.w * kr4.w;
        pdw[col * PST + row] = v.x * kw4.x + v.y * kw4.y + v.z * kw4.z + v.w * kw4.w;
        pn2[col * PST + row] = v.x * v.x + v.y * v.y + v.z * v.z + v.w * v.w;
    }
    __syncthreads();

    // phase B: thread == row; 48 independent b32 reads, register tree sums
    {
        float a0, a1, a2, a3;
        a0 = pdr[0*PST+tid] + pdr[1*PST+tid];  a1 = pdr[2*PST+tid] + pdr[3*PST+tid];
        a2 = pdr[4*PST+tid] + pdr[5*PST+tid];  a3 = pdr[6*PST+tid] + pdr[7*PST+tid];
        float dr = (a0 + a1) + (a2 + a3);
        a0 = pdr[8*PST+tid] + pdr[9*PST+tid];  a1 = pdr[10*PST+tid] + pdr[11*PST+tid];
        a2 = pdr[12*PST+tid] + pdr[13*PST+tid]; a3 = pdr[14*PST+tid] + pdr[15*PST+tid];
        dr += (a0 + a1) + (a2 + a3);
        a0 = pdw[0*PST+tid] + pdw[1*PST+tid];  a1 = pdw[2*PST+tid] + pdw[3*PST+tid];
        a2 = pdw[4*PST+tid] + pdw[5*PST+tid];  a3 = pdw[6*PST+tid] + pdw[7*PST+tid];
        float dw = (a0 + a1) + (a2 + a3);
        a0 = pdw[8*PST+tid] + pdw[9*PST+tid];  a1 = pdw[10*PST+tid] + pdw[11*PST+tid];
        a2 = pdw[12*PST+tid] + pdw[13*PST+tid]; a3 = pdw[14*PST+tid] + pdw[15*PST+tid];
        dw += (a0 + a1) + (a2 + a3);
        a0 = pn2[0*PST+tid] + pn2[1*PST+tid];  a1 = pn2[2*PST+tid] + pn2[3*PST+tid];
        a2 = pn2[4*PST+tid] + pn2[5*PST+tid];  a3 = pn2[6*PST+tid] + pn2[7*PST+tid];
        float n2 = (a0 + a1) + (a2 + a3);
        a0 = pn2[8*PST+tid] + pn2[9*PST+tid];  a1 = pn2[10*PST+tid] + pn2[11*PST+tid];
        a2 = pn2[12*PST+tid] + pn2[13*PST+tid]; a3 = pn2[14*PST+tid] + pn2[15*PST+tid];
        n2 += (a0 + a1) + (a2 + a3);
        float imn = 1.f / fmaxf(sqrtf(n2), EPSV);
        sh_er[1 + tid] = exp2f(1.44269504f * beta_r * (dr * par[0] * imn - 1.f));
        sh_ew[1 + tid] = exp2f(1.44269504f * beta_w * (dw * par[1] * imn - 1.f));
    }
    __syncthreads();

    // conv + sharpen for row s = row0 + tid (fast pow: base > 0)
    float cvr = par[2] * sh_er[tid] + par[3] * sh_er[tid + 1] + par[4] * sh_er[tid + 2];
    float cvw = par[5] * sh_ew[tid] + par[6] * sh_ew[tid + 1] + par[7] * sh_ew[tid + 2];
    float wgr = exp2f(gamma_r * log2f(cvr));
    float wgw = exp2f(gamma_w * log2f(cvw));
    ws[OFF_WGR + (size_t)b * SS + row0 + tid] = wgr;
    ws[OFF_WGW + (size_t)b * SS + row0 + tid] = wgw;

    int w = tid >> 6, lane = tid & 63;
    float rr = wgr, rw2 = wgw;
    #pragma unroll
    for (int off = 32; off >= 1; off >>= 1) {
        rr += __shfl_xor(rr, off);
        rw2 += __shfl_xor(rw2, off);
    }
    if (lane == 0) { lr[w] = rr; lw[w] = rw2; }
    __syncthreads();
    if (tid == 0) {
        ws[OFF_SGRP + b * 64 + chunk] = lr[0] + lr[1] + lr[2] + lr[3];
        ws[OFF_SGWP + b * 64 + chunk] = lw[0] + lw[1] + lw[2] + lw[3];
    }
}

// Final weights; r partials; new_mem = mem*(1-w_w*e)+w_w*a.
__global__ void k_update(const float* __restrict__ mem, float* __restrict__ ws,
                         float* __restrict__ out) {
    int b = blockIdx.x >> 6, chunk = blockIdx.x & 63, tid = threadIdx.x;
    int rowslot = tid >> 4, col = tid & 15;
    const float* P = ws + OFF_P + (size_t)b * 512;
    float4 er4 = *(const float4*)(P + 256 + col * 4);
    float4 ad4 = *(const float4*)(P + 320 + col * 4);

    // reduce per-chunk wgam sums -> 1/sum
    __shared__ float sinv[2];
    if (tid < 64) {
        float v = ws[OFF_SGRP + b * 64 + tid];
        #pragma unroll
        for (int off = 32; off >= 1; off >>= 1) v += __shfl_xor(v, off);
        if (tid == 0) sinv[0] = 1.f / v;
    } else if (tid < 128) {
        float v = ws[OFF_SGWP + b * 64 + (tid - 64)];
        #pragma unroll
        for (int off = 32; off >= 1; off >>= 1) v += __shfl_xor(v, off);
        if (tid == 64) sinv[1] = 1.f / v;
    }
    __syncthreads();
    float isr = sinv[0], isw = sinv[1];

    const float* wgr = ws + OFF_WGR + (size_t)b * SS;
    const float* wgw = ws + OFF_WGW + (size_t)b * SS;
    float* nm = out + 2048 + (size_t)b * SS * 64;
    float4 racc = {0.f, 0.f, 0.f, 0.f};
    int row0 = chunk * 256;
    for (int it = 0; it < 16; ++it) {
        int row = row0 + it * 16 + rowslot;
        float wr = wgr[row] * isr;
        float ww = wgw[row] * isw;
        float4 v = *(const float4*)(mem + ((size_t)b * SS + row) * 64 + col * 4);
        racc.x = fmaf(wr, v.x, racc.x);
        racc.y = fmaf(wr, v.y, racc.y);
        racc.z = fmaf(wr, v.z, racc.z);
        racc.w = fmaf(wr, v.w, racc.w);
        float4 o4;
        o4.x = v.x * (1.f - ww * er4.x) + ww * ad4.x;
        o4.y = v.y * (1.f - ww * er4.y) + ww * ad4.y;
        o4.z = v.z * (1.f - ww * er4.z) + ww * ad4.z;
        o4.w = v.w * (1.f - ww * er4.w) + ww * ad4.w;
        *(float4*)(nm + (size_t)row * 64 + col * 4) = o4;
    }
    __shared__ float4 red[256];
    red[tid] = racc;
    __syncthreads();
    if (tid < 16) {
        float4 a = red[tid];
        for (int rs = 1; rs < 16; ++rs) {
            float4 t2 = red[rs * 16 + tid];
            a.x += t2.x; a.y += t2.y; a.z += t2.z; a.w += t2.w;
        }
        float* rp = ws + OFF_RP + ((size_t)b * 64 + chunk) * 64;
        rp[tid * 4 + 0] = a.x;
        rp[tid * 4 + 1] = a.y;
        rp[tid * 4 + 2] = a.z;
        rp[tid * 4 + 3] = a.w;
    }
}

// output = softmax(concat(h, r) @ W_o.T + b_o); one wave per batch.
__global__ void k_out(const float* __restrict__ ws, const float* __restrict__ W_o,
                      const float* __restrict__ b_o, float* __restrict__ out) {
    int b = blockIdx.x, o = threadIdx.x;  // 64 threads
    __shared__ float sh_r[64];
    float accr = 0.f;
    for (int c = 0; c < 64; ++c) accr += ws[OFF_RP + ((size_t)b * 64 + c) * 64 + o];
    sh_r[o] = accr;
    __syncthreads();
    const float* h = ws + OFF_H + (size_t)b * 512;
    const float* w = W_o + (size_t)o * 576;
    float acc = b_o[o];
    for (int t = 0; t < 512; t++) acc = fmaf(h[t], w[t], acc);
    for (int m = 0; m < 64; m++) acc = fmaf(sh_r[m], w[512 + m], acc);
    float mx = acc;
    #pragma unroll
    for (int off = 32; off >= 1; off >>= 1) mx = fmaxf(mx, __shfl_xor(mx, off));
    float e = expf(acc - mx);
    float sm = e;
    #pragma unroll
    for (int off = 32; off >= 1; off >>= 1) sm += __shfl_xor(sm, off);
    out[b * 64 + o] = e / sm;
}

extern "C" void kernel_launch(void* const* d_in, const int* in_sizes, int n_in,
                              void* d_out, int out_size, void* d_ws, size_t ws_size,
                              hipStream_t stream) {
    const float* x    = (const float*)d_in[0];
    const float* pdo  = (const float*)d_in[1];
    const float* prv  = (const float*)d_in[2];
    const float* mem  = (const float*)d_in[3];
    const float* W_ih = (const float*)d_in[4];
    // d_in[5] = W_hh (unused by reference math)
    const float* b_ih = (const float*)d_in[6];
    const float* b_hh = (const float*)d_in[7];
    const float* W_r  = (const float*)d_in[8];
    const float* b_r  = (const float*)d_in[9];
    const float* W_w  = (const float*)d_in[10];
    const float* b_w  = (const float*)d_in[11];
    const float* W_o  = (const float*)d_in[12];
    const float* b_o  = (const float*)d_in[13];
    float* out = (float*)d_out;
    float* ws  = (float*)d_ws;

    k_lstm<<<BB * 512 / 4, 256, 0, stream>>>(x, pdo, prv, W_ih, b_ih, b_hh, ws);
    k_heads<<<(BB * 268) / 4, 256, 0, stream>>>(W_r, b_r, W_w, b_w, ws);
    k_scorewgam<<<BB * 64, 256, 0, stream>>>(mem, ws);
    k_update<<<BB * 64, 256, 0, stream>>>(mem, ws, out);
    k_out<<<BB, 64, 0, stream>>>(ws, W_o, b_o, out);
}